// Round 8
// baseline (461.771 us; speedup 1.0000x reference)
//
#include <hip/hip_runtime.h>
#include <hip/hip_bf16.h>

#define DIM 128
#define BN_EPS 1e-5f
#define NSTRIPE 32

typedef unsigned short ushortT;
typedef __attribute__((ext_vector_type(8))) short short8;
typedef __attribute__((ext_vector_type(4))) float floatx4;

__device__ __forceinline__ float bflo(unsigned u) { return __uint_as_float(u << 16); }
__device__ __forceinline__ float bfhi(unsigned u) { return __uint_as_float(u & 0xffff0000u); }
__device__ __forceinline__ float bf2f(ushortT h) { return __uint_as_float(((unsigned)h) << 16); }
__device__ __forceinline__ ushortT f2bf(float f) {
    unsigned x = __float_as_uint(f);
    unsigned r = (x + 0x7fff + ((x >> 16) & 1)) >> 16;
    return (ushortT)r;
}
__device__ __forceinline__ void decode8(const unsigned* ap, short8& hi, short8& lo) {
#pragma unroll
    for (int j = 0; j < 8; ++j) {
        hi[j] = (short)(ap[j] >> 16);
        lo[j] = (short)(ap[j] & 0xffffu);
    }
}
__device__ __forceinline__ void acc8(float* a, uint4 v) {
    a[0] += bflo(v.x); a[1] += bfhi(v.x);
    a[2] += bflo(v.y); a[3] += bfhi(v.y);
    a[4] += bflo(v.z); a[5] += bfhi(v.z);
    a[6] += bflo(v.w); a[7] += bfhi(v.w);
}

// ---------------- CSR build ----------------
__global__ __launch_bounds__(256) void hist_kernel(
    const int* __restrict__ dst, int* __restrict__ deg, int E)
{
    int e = blockIdx.x * 256 + threadIdx.x;
    if (e < E) atomicAdd(&deg[dst[e]], 1);
}

// ---- range alloc: block-local scan + 1 atomic per block; ranges need not be in
//      node order (replaces scan1+scan2+scan3, 3 dispatches -> 1) ----
__global__ __launch_bounds__(256) void alloc_kernel(
    const int* __restrict__ deg, int* __restrict__ rstart,
    int* __restrict__ cur, int* __restrict__ total, int N)
{
    __shared__ int s[256];
    __shared__ int base;
    int t = threadIdx.x;
    int i = blockIdx.x * 256 + t;
    int v = (i < N) ? deg[i] : 0;
    s[t] = v;
    __syncthreads();
#pragma unroll
    for (int off = 1; off < 256; off <<= 1) {
        int u = (t >= off) ? s[t - off] : 0;
        __syncthreads();
        s[t] += u;
        __syncthreads();
    }
    if (t == 255) base = atomicAdd(total, s[255]);
    __syncthreads();
    if (i < N) {
        int pos = base + s[t] - v;
        rstart[i] = pos;
        cur[i] = pos;
    }
}

__global__ __launch_bounds__(256) void fill_kernel(
    const int* __restrict__ src, const int* __restrict__ dst,
    int* __restrict__ cur, int* __restrict__ eidx, int E)
{
    int e = blockIdx.x * 256 + threadIdx.x;
    if (e < E) {
        int pos = atomicAdd(&cur[dst[e]], 1);
        eidx[pos] = src[e];
    }
}

// ---- prep: weights->bf16 planes + x->bf16 + zero-fill ----
__global__ __launch_bounds__(256) void prep_kernel(
    const float* __restrict__ cw1, const float* __restrict__ cw2,
    const float* __restrict__ nmu, const float* __restrict__ nlv,
    const float* __restrict__ gmu, const float* __restrict__ glv,
    ushortT* __restrict__ whi, ushortT* __restrict__ wlo,
    const float* __restrict__ x, ushortT* __restrict__ xb, int n8, int cxBlocks,
    float4* __restrict__ zsbuf, int sbufQ,
    float4* __restrict__ zslots, int slotsQ,
    float4* __restrict__ zdeg, int degQ,
    float4* __restrict__ zstats, int statsQ)
{
    int b = blockIdx.x, t = threadIdx.x;
    if (b < 640) {
        int tid = b * 256 + t; // 10*16384
        int mat = tid >> 14;
        int i   = tid & 16383;
        int n = i >> 7, k = i & 127;
        const float* Wm = (mat < 3) ? cw1 + (size_t)mat * 16384
                        : (mat < 6) ? cw2 + (size_t)(mat - 3) * 16384
                        : (mat == 6) ? nmu : (mat == 7) ? nlv
                        : (mat == 8) ? gmu : glv;
        float w = Wm[k * DIM + n];
        ushortT h = f2bf(w);
        whi[(size_t)mat * 16384 + i] = h;
        wlo[(size_t)mat * 16384 + i] = f2bf(w - bf2f(h));
    } else if (b < 640 + cxBlocks) {
        int i = (b - 640) * 256 + t;
        if (i < n8) {
            const float4* xp = (const float4*)x;
            float4 a = xp[2 * i], bb = xp[2 * i + 1];
            uint4 o;
            o.x = (unsigned)f2bf(a.x) | ((unsigned)f2bf(a.y) << 16);
            o.y = (unsigned)f2bf(a.z) | ((unsigned)f2bf(a.w) << 16);
            o.z = (unsigned)f2bf(bb.x) | ((unsigned)f2bf(bb.y) << 16);
            o.w = (unsigned)f2bf(bb.z) | ((unsigned)f2bf(bb.w) << 16);
            ((uint4*)xb)[i] = o;
        }
    } else {
        int q = (b - 640 - cxBlocks) * 256 + t;
        float4 z = make_float4(0.f, 0.f, 0.f, 0.f);
        if (q < sbufQ) zsbuf[q] = z;
        else if ((q -= sbufQ) < slotsQ) zslots[q] = z;
        else if ((q -= slotsQ) < degQ) zdeg[q] = z;
        else if ((q -= degQ) < statsQ) zstats[q] = z;
    }
}

// ---- fused GIN layer (round-3 known-good; row ranges now rstart/deg) ----
__global__ __launch_bounds__(256) void layer_fused_kernel(
    const ushortT* __restrict__ Xb, const int* __restrict__ rstart,
    const int* __restrict__ degp, const int* __restrict__ eidx,
    const float* __restrict__ sprev,
    const float* __restrict__ gamma, const float* __restrict__ beta,
    const ushortT* __restrict__ W1hi, const ushortT* __restrict__ W1lo,
    const float* __restrict__ b1,
    const ushortT* __restrict__ W2hi, const ushortT* __restrict__ W2lo,
    const float* __restrict__ b2,
    ushortT* __restrict__ rout, float* __restrict__ sdst,
    int M, float invM)
{
    __shared__ unsigned As[32][DIM + 4];
    __shared__ float ls[DIM], lsq[DIM];
    __shared__ float pstat[256];
    int t = threadIdx.x;
    int wave = t >> 6, lane = t & 63, quad = lane >> 4, l16 = lane & 15;
    int m0 = blockIdx.x * 32;

    if (sprev) {
        float s = 0.f;
#pragma unroll
        for (int i = 0; i < NSTRIPE; ++i) s += sprev[i * 256 + t];
        pstat[t] = s;
    }
    if (t < DIM) { ls[t] = 0.f; lsq[t] = 0.f; }
    __syncthreads();

    // ---- gather phase: 8 lanes per node, 16 cols each; edge loop unrolled x4 ----
    {
        int nloc = t >> 3;
        int c0   = (t & 7) * 16;
        int node = m0 + nloc;
        float acc[16];
#pragma unroll
        for (int j = 0; j < 16; ++j) acc[j] = 0.f;
        if (node < M) {
            int b = rstart[node];
            int dg = degp[node];
            int e = b + dg;
            const ushortT* xrow = Xb + (size_t)node * DIM + c0;
            acc8(&acc[0], *(const uint4*)(xrow));
            acc8(&acc[8], *(const uint4*)(xrow + 8));
            int i = b;
            for (; i + 4 <= e; i += 4) {
                int s0 = eidx[i], s1 = eidx[i + 1], s2 = eidx[i + 2], s3 = eidx[i + 3];
                const ushortT* p0 = Xb + (size_t)s0 * DIM + c0;
                const ushortT* p1 = Xb + (size_t)s1 * DIM + c0;
                const ushortT* p2 = Xb + (size_t)s2 * DIM + c0;
                const ushortT* p3 = Xb + (size_t)s3 * DIM + c0;
                uint4 v00 = *(const uint4*)(p0), v01 = *(const uint4*)(p0 + 8);
                uint4 v10 = *(const uint4*)(p1), v11 = *(const uint4*)(p1 + 8);
                uint4 v20 = *(const uint4*)(p2), v21 = *(const uint4*)(p2 + 8);
                uint4 v30 = *(const uint4*)(p3), v31 = *(const uint4*)(p3 + 8);
                acc8(&acc[0], v00); acc8(&acc[8], v01);
                acc8(&acc[0], v10); acc8(&acc[8], v11);
                acc8(&acc[0], v20); acc8(&acc[8], v21);
                acc8(&acc[0], v30); acc8(&acc[8], v31);
            }
            for (; i < e; ++i) {
                const ushortT* sp = Xb + (size_t)eidx[i] * DIM + c0;
                acc8(&acc[0], *(const uint4*)(sp));
                acc8(&acc[8], *(const uint4*)(sp + 8));
            }
            if (sprev) {
                float cnt = (float)(dg + 1);
#pragma unroll
                for (int jq = 0; jq < 4; ++jq) {
                    int c = c0 + jq * 4;
                    float4 sm = *(const float4*)&pstat[c];
                    float4 sq = *(const float4*)&pstat[128 + c];
                    float4 gm = *(const float4*)(gamma + c);
                    float4 bt = *(const float4*)(beta + c);
                    float m, sc;
                    m = sm.x * invM; sc = gm.x * rsqrtf(sq.x * invM - m * m + BN_EPS);
                    acc[jq * 4 + 0] = sc * acc[jq * 4 + 0] + cnt * (bt.x - sc * m);
                    m = sm.y * invM; sc = gm.y * rsqrtf(sq.y * invM - m * m + BN_EPS);
                    acc[jq * 4 + 1] = sc * acc[jq * 4 + 1] + cnt * (bt.y - sc * m);
                    m = sm.z * invM; sc = gm.z * rsqrtf(sq.z * invM - m * m + BN_EPS);
                    acc[jq * 4 + 2] = sc * acc[jq * 4 + 2] + cnt * (bt.z - sc * m);
                    m = sm.w * invM; sc = gm.w * rsqrtf(sq.w * invM - m * m + BN_EPS);
                    acc[jq * 4 + 3] = sc * acc[jq * 4 + 3] + cnt * (bt.w - sc * m);
                }
            }
        }
        unsigned pk[16];
#pragma unroll
        for (int j = 0; j < 16; ++j) {
            ushortT h = f2bf(acc[j]);
            ushortT l = f2bf(acc[j] - bf2f(h));
            pk[j] = ((unsigned)h << 16) | l;
        }
#pragma unroll
        for (int j4 = 0; j4 < 4; ++j4)
            *(uint4*)&As[nloc][c0 + j4 * 4] = *(uint4*)&pk[j4 * 4];
    }
    __syncthreads();

    int cbase = wave * 32;
    floatx4 acc[2][2];
#pragma unroll
    for (int mt = 0; mt < 2; ++mt)
#pragma unroll
        for (int nt = 0; nt < 2; ++nt)
            acc[mt][nt] = (floatx4){0.f, 0.f, 0.f, 0.f};

    // ---- GEMM1 ----
#pragma unroll
    for (int ks = 0; ks < 4; ++ks) {
        int k0 = ks * 32 + quad * 8;
        short8 bhi[2], blo[2];
#pragma unroll
        for (int nt = 0; nt < 2; ++nt) {
            const size_t woff = (size_t)(cbase + nt * 16 + l16) * DIM + k0;
            bhi[nt] = *(const short8*)(W1hi + woff);
            blo[nt] = *(const short8*)(W1lo + woff);
        }
#pragma unroll
        for (int mt = 0; mt < 2; ++mt) {
            int lr = mt * 16 + l16;
            unsigned ap[8];
            *(uint4*)&ap[0] = *(const uint4*)&As[lr][k0];
            *(uint4*)&ap[4] = *(const uint4*)&As[lr][k0 + 4];
            short8 ahi, alo;
            decode8(ap, ahi, alo);
#pragma unroll
            for (int nt = 0; nt < 2; ++nt) {
                acc[mt][nt] = __builtin_amdgcn_mfma_f32_16x16x32_bf16(ahi, bhi[nt], acc[mt][nt], 0, 0, 0);
                acc[mt][nt] = __builtin_amdgcn_mfma_f32_16x16x32_bf16(alo, bhi[nt], acc[mt][nt], 0, 0, 0);
                acc[mt][nt] = __builtin_amdgcn_mfma_f32_16x16x32_bf16(ahi, blo[nt], acc[mt][nt], 0, 0, 0);
            }
        }
    }
    __syncthreads();

    // epilogue 1 -> LDS
#pragma unroll
    for (int nt = 0; nt < 2; ++nt) {
        int col = cbase + nt * 16 + l16;
        float bcol = b1[col];
#pragma unroll
        for (int mt = 0; mt < 2; ++mt)
#pragma unroll
            for (int r = 0; r < 4; ++r) {
                int lr = mt * 16 + quad * 4 + r;
                float v = fmaxf(acc[mt][nt][r] + bcol, 0.f);
                ushortT hv = f2bf(v);
                ushortT lv = f2bf(v - bf2f(hv));
                As[lr][col] = ((unsigned)hv << 16) | lv;
            }
    }
    __syncthreads();

    // ---- GEMM2 ----
#pragma unroll
    for (int mt = 0; mt < 2; ++mt)
#pragma unroll
        for (int nt = 0; nt < 2; ++nt)
            acc[mt][nt] = (floatx4){0.f, 0.f, 0.f, 0.f};

#pragma unroll
    for (int ks = 0; ks < 4; ++ks) {
        int k0 = ks * 32 + quad * 8;
        short8 bhi[2], blo[2];
#pragma unroll
        for (int nt = 0; nt < 2; ++nt) {
            const size_t woff = (size_t)(cbase + nt * 16 + l16) * DIM + k0;
            bhi[nt] = *(const short8*)(W2hi + woff);
            blo[nt] = *(const short8*)(W2lo + woff);
        }
#pragma unroll
        for (int mt = 0; mt < 2; ++mt) {
            int lr = mt * 16 + l16;
            unsigned ap[8];
            *(uint4*)&ap[0] = *(const uint4*)&As[lr][k0];
            *(uint4*)&ap[4] = *(const uint4*)&As[lr][k0 + 4];
            short8 ahi, alo;
            decode8(ap, ahi, alo);
#pragma unroll
            for (int nt = 0; nt < 2; ++nt) {
                acc[mt][nt] = __builtin_amdgcn_mfma_f32_16x16x32_bf16(ahi, bhi[nt], acc[mt][nt], 0, 0, 0);
                acc[mt][nt] = __builtin_amdgcn_mfma_f32_16x16x32_bf16(alo, bhi[nt], acc[mt][nt], 0, 0, 0);
                acc[mt][nt] = __builtin_amdgcn_mfma_f32_16x16x32_bf16(ahi, blo[nt], acc[mt][nt], 0, 0, 0);
            }
        }
    }
    // epilogue 2
#pragma unroll
    for (int nt = 0; nt < 2; ++nt) {
        int col = cbase + nt * 16 + l16;
        float bcol = b2[col];
        float s = 0.f, sq = 0.f;
#pragma unroll
        for (int mt = 0; mt < 2; ++mt)
#pragma unroll
            for (int r = 0; r < 4; ++r) {
                int gr = m0 + mt * 16 + quad * 4 + r;
                if (gr < M) {
                    float v = fmaxf(acc[mt][nt][r] + bcol, 0.f);
                    rout[(size_t)gr * DIM + col] = f2bf(v);
                    s += v;
                    sq += v * v;
                }
            }
        s  += __shfl_xor(s, 16);  s  += __shfl_xor(s, 32);
        sq += __shfl_xor(sq, 16); sq += __shfl_xor(sq, 32);
        if (quad == 0) {
            atomicAdd(&ls[col], s);
            atomicAdd(&lsq[col], sq);
        }
    }
    __syncthreads();
    float* dstp = sdst + (size_t)(blockIdx.x & (NSTRIPE - 1)) * 256;
    if (t < 128) atomicAdd(&dstp[t], ls[t]);
    else         atomicAdd(&dstp[t], lsq[t - 128]);
}

// ---- fused weigh+split+node-heads (round-7, verified) ----
__global__ __launch_bounds__(256) void weigh_heads_kernel(
    const ushortT* __restrict__ R, const int* __restrict__ batch,
    const float* __restrict__ sprev,
    const float* __restrict__ gamma, const float* __restrict__ beta,
    const float* __restrict__ sw_w, const float* __restrict__ sw_b,
    float* __restrict__ slots,
    const ushortT* __restrict__ WAhi, const ushortT* __restrict__ WAlo,
    const float* __restrict__ bA, ushortT* __restrict__ hA, float* __restrict__ sdstA,
    const ushortT* __restrict__ WBhi, const ushortT* __restrict__ WBlo,
    const float* __restrict__ bB, ushortT* __restrict__ hB, float* __restrict__ sdstB,
    int N, float invM)
{
    __shared__ unsigned As[64][DIM + 4];
    __shared__ float pstat[256];
    __shared__ float part[256];
    __shared__ float wsh[64];
    __shared__ float lsA[DIM], lsqA[DIM], lsB[DIM], lsqB[DIM];
    int t = threadIdx.x;
    int wave = t >> 6, lane = t & 63, quad = lane >> 4, l16 = lane & 15;
    int m0 = blockIdx.x * 64;

    {
        float s = 0.f;
#pragma unroll
        for (int i = 0; i < NSTRIPE; ++i) s += sprev[i * 256 + t];
        pstat[t] = s;
    }
    if (t < DIM) { lsA[t] = 0.f; lsqA[t] = 0.f; lsB[t] = 0.f; lsqB[t] = 0.f; }
    __syncthreads();

    // phase A: per-row dot for w
    {
        int row = m0 + (t >> 2);
        int cs  = (t & 3) * 32;
        float d = 0.f;
        if (row < N) {
            for (int c = cs; c < cs + 32; c += 4) {
                uint2 u = *(const uint2*)(R + (size_t)row * DIM + c);
                float rv[4] = {bflo(u.x), bfhi(u.x), bflo(u.y), bfhi(u.y)};
                float4 sm = *(const float4*)&pstat[c];
                float4 sq = *(const float4*)&pstat[128 + c];
                float4 gm = *(const float4*)(gamma + c);
                float4 bt = *(const float4*)(beta + c);
                float4 sw = *(const float4*)(sw_w + c);
                float m, sc;
                m = sm.x * invM; sc = gm.x * rsqrtf(sq.x * invM - m * m + BN_EPS);
                d += (sc * (rv[0] - m) + bt.x) * sw.x;
                m = sm.y * invM; sc = gm.y * rsqrtf(sq.y * invM - m * m + BN_EPS);
                d += (sc * (rv[1] - m) + bt.y) * sw.y;
                m = sm.z * invM; sc = gm.z * rsqrtf(sq.z * invM - m * m + BN_EPS);
                d += (sc * (rv[2] - m) + bt.z) * sw.z;
                m = sm.w * invM; sc = gm.w * rsqrtf(sq.w * invM - m * m + BN_EPS);
                d += (sc * (rv[3] - m) + bt.w) * sw.w;
            }
        }
        part[t] = d;
    }
    __syncthreads();
    if (t < 64) {
        float dd = part[4 * t] + part[4 * t + 1] + part[4 * t + 2] + part[4 * t + 3];
        wsh[t] = 1.0f / (1.0f + expf(-(dd + sw_b[0])));
    }
    __syncthreads();

    // phase B: noisy -> LDS, slots += w*bn(r)
    {
        int c    = t & 127;
        int half = t >> 7;
        float m   = pstat[c] * invM;
        float var = pstat[128 + c] * invM - m * m;
        float sc  = gamma[c] * rsqrtf(var + BN_EPS);
        float sh  = beta[c] - sc * m;
        int curg = -1;
        float acc = 0.f;
        for (int r = half; r < 64; r += 2) {
            int row = m0 + r;
            if (row < N) {
                float xv = sc * bf2f(R[(size_t)row * DIM + c]) + sh;
                float w  = wsh[r];
                float nv = (1.f - w) * xv;
                ushortT hv = f2bf(nv);
                ushortT lv = f2bf(nv - bf2f(hv));
                As[r][c] = ((unsigned)hv << 16) | lv;
                int g = batch[row];
                if (g != curg) {
                    if (curg >= 0) atomicAdd(&slots[(size_t)curg * DIM + c], acc);
                    curg = g;
                    acc = 0.f;
                }
                acc += w * xv;
            } else {
                As[r][c] = 0;
            }
        }
        if (curg >= 0) atomicAdd(&slots[(size_t)curg * DIM + c], acc);
    }
    __syncthreads();

    // phase C: dual-head GEMM from LDS
    int cbase = wave * 32;
    floatx4 accA[4][2], accB[4][2];
#pragma unroll
    for (int mt = 0; mt < 4; ++mt)
#pragma unroll
        for (int nt = 0; nt < 2; ++nt) {
            accA[mt][nt] = (floatx4){0.f, 0.f, 0.f, 0.f};
            accB[mt][nt] = (floatx4){0.f, 0.f, 0.f, 0.f};
        }

    for (int ks = 0; ks < 4; ++ks) {
        int k0 = ks * 32 + quad * 8;
        short8 bAhi[2], bAlo[2], bBhi[2], bBlo[2];
#pragma unroll
        for (int nt = 0; nt < 2; ++nt) {
            const size_t woff = (size_t)(cbase + nt * 16 + l16) * DIM + k0;
            bAhi[nt] = *(const short8*)(WAhi + woff);
            bAlo[nt] = *(const short8*)(WAlo + woff);
            bBhi[nt] = *(const short8*)(WBhi + woff);
            bBlo[nt] = *(const short8*)(WBlo + woff);
        }
#pragma unroll
        for (int mt = 0; mt < 4; ++mt) {
            int lr = mt * 16 + l16;
            unsigned ap[8];
            *(uint4*)&ap[0] = *(const uint4*)&As[lr][k0];
            *(uint4*)&ap[4] = *(const uint4*)&As[lr][k0 + 4];
            short8 ahi, alo;
            decode8(ap, ahi, alo);
#pragma unroll
            for (int nt = 0; nt < 2; ++nt) {
                accA[mt][nt] = __builtin_amdgcn_mfma_f32_16x16x32_bf16(ahi, bAhi[nt], accA[mt][nt], 0, 0, 0);
                accA[mt][nt] = __builtin_amdgcn_mfma_f32_16x16x32_bf16(alo, bAhi[nt], accA[mt][nt], 0, 0, 0);
                accA[mt][nt] = __builtin_amdgcn_mfma_f32_16x16x32_bf16(ahi, bAlo[nt], accA[mt][nt], 0, 0, 0);
                accB[mt][nt] = __builtin_amdgcn_mfma_f32_16x16x32_bf16(ahi, bBhi[nt], accB[mt][nt], 0, 0, 0);
                accB[mt][nt] = __builtin_amdgcn_mfma_f32_16x16x32_bf16(alo, bBhi[nt], accB[mt][nt], 0, 0, 0);
                accB[mt][nt] = __builtin_amdgcn_mfma_f32_16x16x32_bf16(ahi, bBlo[nt], accB[mt][nt], 0, 0, 0);
            }
        }
    }

#pragma unroll
    for (int nt = 0; nt < 2; ++nt) {
        int col = cbase + nt * 16 + l16;
        float bcA = bA[col], bcB = bB[col];
        float sA = 0.f, sqA = 0.f, sB = 0.f, sqB = 0.f;
#pragma unroll
        for (int mt = 0; mt < 4; ++mt)
#pragma unroll
            for (int r = 0; r < 4; ++r) {
                int gr = m0 + mt * 16 + quad * 4 + r;
                if (gr < N) {
                    size_t off = (size_t)gr * DIM + col;
                    float vA = fmaxf(accA[mt][nt][r] + bcA, 0.f);
                    float vB = fmaxf(accB[mt][nt][r] + bcB, 0.f);
                    hA[off] = f2bf(vA);
                    hB[off] = f2bf(vB);
                    sA += vA; sqA += vA * vA;
                    sB += vB; sqB += vB * vB;
                }
            }
        sA += __shfl_xor(sA, 16);  sA += __shfl_xor(sA, 32);
        sqA += __shfl_xor(sqA, 16); sqA += __shfl_xor(sqA, 32);
        sB += __shfl_xor(sB, 16);  sB += __shfl_xor(sB, 32);
        sqB += __shfl_xor(sqB, 16); sqB += __shfl_xor(sqB, 32);
        if (quad == 0) {
            atomicAdd(&lsA[col], sA);
            atomicAdd(&lsqA[col], sqA);
            atomicAdd(&lsB[col], sB);
            atomicAdd(&lsqB[col], sqB);
        }
    }
    __syncthreads();
    int stripe = blockIdx.x & (NSTRIPE - 1);
    float* dA = sdstA + (size_t)stripe * 256;
    float* dB = sdstB + (size_t)stripe * 256;
    if (t < 128) { atomicAdd(&dA[t], lsA[t]); atomicAdd(&dB[t], lsB[t]); }
    else         { atomicAdd(&dA[t], lsqA[t - 128]); atomicAdd(&dB[t], lsqB[t - 128]); }
}

// ---- BN apply for node heads: in-block stripe merge + grid-stride (merge_stats2 folded in) ----
__global__ __launch_bounds__(256) void bn_dual_bf16_kernel(
    const ushortT* __restrict__ RA, float* __restrict__ OA, const float* __restrict__ sbA,
    const float* __restrict__ gA, const float* __restrict__ bA,
    const ushortT* __restrict__ RB, float* __restrict__ OB, const float* __restrict__ sbB,
    const float* __restrict__ gB, const float* __restrict__ bB,
    int M, int nbh)
{
    __shared__ float pstat[256];
    __shared__ float scL[128], shL[128];
    int bb = blockIdx.x;
    const ushortT* R; float* O; const float* sb; const float* gamma; const float* beta;
    if (bb < nbh) { R = RA; O = OA; sb = sbA; gamma = gA; beta = bA; }
    else { bb -= nbh; R = RB; O = OB; sb = sbB; gamma = gB; beta = bB; }
    int t = threadIdx.x;
    {
        float s = 0.f;
#pragma unroll
        for (int i = 0; i < NSTRIPE; ++i) s += sb[i * 256 + t];
        pstat[t] = s;
    }
    __syncthreads();
    float invM = 1.0f / (float)M;
    if (t < 128) {
        float m   = pstat[t] * invM;
        float var = pstat[128 + t] * invM - m * m;
        float sc  = gamma[t] * rsqrtf(var + BN_EPS);
        scL[t] = sc;
        shL[t] = beta[t] - sc * m;
    }
    __syncthreads();
    int Q = M * 32;
    for (int idx = bb * 256 + t; idx < Q; idx += nbh * 256) {
        int c4 = idx & 31;
        uint2 u = ((const uint2*)R)[idx];
        float o[4] = {bflo(u.x), bfhi(u.x), bflo(u.y), bfhi(u.y)};
#pragma unroll
        for (int j = 0; j < 4; ++j) {
            int c = c4 * 4 + j;
            o[j] = scL[c] * o[j] + shL[c];
        }
        ((float4*)O)[idx] = make_float4(o[0], o[1], o[2], o[3]);
    }
}

// ---- graph-head GEMMs + in-kernel BN via last-block pattern (bn_dual_f32 folded in) ----
__global__ __launch_bounds__(256) void gemm_graph_dual_bn_kernel(
    const float* __restrict__ A32,
    const ushortT* __restrict__ W8hi, const ushortT* __restrict__ W8lo,
    const float* __restrict__ b8, float* __restrict__ C8, float* __restrict__ st8,
    const float* __restrict__ g8, const float* __restrict__ be8, int* __restrict__ cnt8,
    const ushortT* __restrict__ W9hi, const ushortT* __restrict__ W9lo,
    const float* __restrict__ b9, float* __restrict__ C9, float* __restrict__ st9,
    const float* __restrict__ g9, const float* __restrict__ be9, int* __restrict__ cnt9,
    int M, int nb)
{
    __shared__ float ls[DIM], lsq[DIM];
    __shared__ int lastB;
    int bb = blockIdx.x;
    const ushortT* Whi; const ushortT* Wlo; const float* bias; float* C; float* st;
    const float* gamma; const float* beta; int* cnt;
    if (bb < nb) { Whi = W8hi; Wlo = W8lo; bias = b8; C = C8; st = st8; gamma = g8; beta = be8; cnt = cnt8; }
    else { bb -= nb; Whi = W9hi; Wlo = W9lo; bias = b9; C = C9; st = st9; gamma = g9; beta = be9; cnt = cnt9; }

    int t     = threadIdx.x;
    int wave  = t >> 6;
    int lane  = t & 63;
    int quad  = lane >> 4;
    int l16   = lane & 15;
    int m0    = bb * 64;
    int cbase = wave * 32;

    if (t < DIM) { ls[t] = 0.f; lsq[t] = 0.f; }
    __syncthreads();

    floatx4 acc[4][2];
#pragma unroll
    for (int mt = 0; mt < 4; ++mt)
#pragma unroll
        for (int nt = 0; nt < 2; ++nt)
            acc[mt][nt] = (floatx4){0.f, 0.f, 0.f, 0.f};

    for (int ks = 0; ks < 4; ++ks) {
        int k0 = ks * 32 + quad * 8;
        short8 bhi[2], blo[2];
#pragma unroll
        for (int nt = 0; nt < 2; ++nt) {
            const size_t woff = (size_t)(cbase + nt * 16 + l16) * DIM + k0;
            bhi[nt] = *(const short8*)(Whi + woff);
            blo[nt] = *(const short8*)(Wlo + woff);
        }
#pragma unroll
        for (int mt = 0; mt < 4; ++mt) {
            int row = m0 + mt * 16 + l16;
            short8 ahi = {0,0,0,0,0,0,0,0};
            short8 alo = {0,0,0,0,0,0,0,0};
            if (row < M) {
                float av[8];
                *(float4*)&av[0] = *(const float4*)(A32 + (size_t)row * DIM + k0);
                *(float4*)&av[4] = *(const float4*)(A32 + (size_t)row * DIM + k0 + 4);
#pragma unroll
                for (int j = 0; j < 8; ++j) {
                    ushortT hv = f2bf(av[j]);
                    ahi[j] = (short)hv;
                    alo[j] = (short)f2bf(av[j] - bf2f(hv));
                }
            }
#pragma unroll
            for (int nt = 0; nt < 2; ++nt) {
                acc[mt][nt] = __builtin_amdgcn_mfma_f32_16x16x32_bf16(ahi, bhi[nt], acc[mt][nt], 0, 0, 0);
                acc[mt][nt] = __builtin_amdgcn_mfma_f32_16x16x32_bf16(alo, bhi[nt], acc[mt][nt], 0, 0, 0);
                acc[mt][nt] = __builtin_amdgcn_mfma_f32_16x16x32_bf16(ahi, blo[nt], acc[mt][nt], 0, 0, 0);
            }
        }
    }

#pragma unroll
    for (int nt = 0; nt < 2; ++nt) {
        int col = cbase + nt * 16 + l16;
        float bcol = bias[col];
        float s = 0.f, sq = 0.f;
#pragma unroll
        for (int mt = 0; mt < 4; ++mt)
#pragma unroll
            for (int r = 0; r < 4; ++r) {
                int gr = m0 + mt * 16 + quad * 4 + r;
                if (gr < M) {
                    float v = fmaxf(acc[mt][nt][r] + bcol, 0.f);
                    C[(size_t)gr * DIM + col] = v;
                    s += v;
                    sq += v * v;
                }
            }
        s  += __shfl_xor(s, 16);  s  += __shfl_xor(s, 32);
        sq += __shfl_xor(sq, 16); sq += __shfl_xor(sq, 32);
        if (quad == 0) {
            atomicAdd(&ls[col], s);
            atomicAdd(&lsq[col], sq);
        }
    }
    __syncthreads();
    if (t < DIM) {
        atomicAdd(&st[t], ls[t]);
        atomicAdd(&st[DIM + t], lsq[t]);
    }
    // release: make this block's C stores + stat atomics visible, then arrive
    __threadfence();
    if (t == 0) lastB = (atomicAdd(cnt, 1) == nb - 1) ? 1 : 0;
    __syncthreads();
    if (lastB) {
        __threadfence(); // acquire
        float invG = 1.0f / (float)M;
        for (int idx = t; idx < M * 32; idx += 256) {
            int c4 = idx & 31;
            float4 v = ((const float4*)C)[idx];
            float o[4] = {v.x, v.y, v.z, v.w};
#pragma unroll
            for (int j = 0; j < 4; ++j) {
                int c = c4 * 4 + j;
                float m   = st[c] * invG;
                float var = st[DIM + c] * invG - m * m;
                float sc  = gamma[c] * rsqrtf(var + BN_EPS);
                o[j] = sc * (o[j] - m) + beta[c];
            }
            ((float4*)C)[idx] = make_float4(o[0], o[1], o[2], o[3]);
        }
    }
}

extern "C" void kernel_launch(void* const* d_in, const int* in_sizes, int n_in,
                              void* d_out, int out_size, void* d_ws, size_t ws_size,
                              hipStream_t stream)
{
    const float* x      = (const float*)d_in[0];
    const int*   src    = (const int*)d_in[1];
    const int*   dst    = (const int*)d_in[2];
    const int*   batch  = (const int*)d_in[3];
    const float* cw1    = (const float*)d_in[5];
    const float* cb1    = (const float*)d_in[6];
    const float* cw2    = (const float*)d_in[7];
    const float* cb2    = (const float*)d_in[8];
    const float* bng    = (const float*)d_in[9];
    const float* bnb    = (const float*)d_in[10];
    const float* sw_w   = (const float*)d_in[11];
    const float* sw_b   = (const float*)d_in[12];
    const float* nmu_b  = (const float*)d_in[14];
    const float* nlv_b  = (const float*)d_in[16];
    const float* gmu_b  = (const float*)d_in[18];
    const float* glv_b  = (const float*)d_in[20];
    const float* hgam   = (const float*)d_in[21];
    const float* hbet   = (const float*)d_in[22];
    const float* nmu_w  = (const float*)d_in[13];
    const float* nlv_w  = (const float*)d_in[15];
    const float* gmu_w  = (const float*)d_in[17];
    const float* glv_w  = (const float*)d_in[19];

    const int N = in_sizes[0] / DIM;
    const int E = in_sizes[1];
    const int G = (out_size / DIM - 2 * N) / 2;

    float* out0 = (float*)d_out;
    float* out1 = out0 + (size_t)N * DIM;
    float* out2 = out1 + (size_t)N * DIM;
    float* out3 = out2 + (size_t)G * DIM;

    // ---- workspace layout ----
    char* wp = (char*)d_ws;
    auto alloc = [&](size_t bytes) {
        char* p = wp;
        wp += (bytes + 255) & ~(size_t)255;
        return p;
    };
    ushortT*  xbf   = (ushortT*)alloc((size_t)N * DIM * 2);  // layer-0 input; later hB
    ushortT*  rA    = (ushortT*)alloc((size_t)N * DIM * 2);  // layer ping; final r
    ushortT*  rB    = (ushortT*)alloc((size_t)N * DIM * 2);  // layer pong; later hA
    unsigned* noisyP= (unsigned*)alloc((size_t)N * DIM * 4); // CSR temps overlay (deg stays live through layers)
    ushortT*  whi   = (ushortT*)alloc((size_t)10 * 16384 * 2);
    ushortT*  wlo   = (ushortT*)alloc((size_t)10 * 16384 * 2);
    float* slots    = (float*)alloc((size_t)G * DIM * 4);
    float* stats    = (float*)alloc((size_t)8 * 256 * 4);          // [sum|sq] x7 + counters page
    float* sbuf     = (float*)alloc((size_t)5 * NSTRIPE * 256 * 4);// stripe bufs x5
    int* rstart     = (int*)alloc((size_t)(N + 2) * 4);
    int* eidx       = (int*)alloc((size_t)E * 4);
    // CSR temps overlay in noisyP (region unused after fill; deg read by layers)
    int* deg   = (int*)noisyP;
    int* iscan = deg + N;      // unused (kept for layout stability)
    int* bsum  = iscan + N;    // unused
    int* cur   = bsum + 256;
    (void)iscan; (void)bsum;

    auto SB = [&](int i) { return sbuf + (size_t)i * NSTRIPE * 256; };
    float* SS5 = stats + (size_t)5 * 256;
    float* SS6 = stats + (size_t)6 * 256;
    int*   cnts = (int*)(stats + (size_t)7 * 256); // [0]=alloc total, [1]=head8 arrivals, [2]=head9 arrivals

    const int edge_blocks  = (E + 255) / 256;
    const int scan_blocks  = (N + 255) / 256;
    const int layer_blocks = (N + 31) / 32;
    const int heads_blocks = (N + 63) / 64;
    const int g16_blocks   = (N * 16 + 255) / 256;
    const float invN = 1.0f / (float)N;

    // zero-region geometry (float4 quads)
    const int sbufQ  = (5 * NSTRIPE * 256) / 4;
    const int slotsQ = (G * DIM) / 4;
    const int degQ   = (N + 3) / 4;      // may spill a few ints into noisyP body: safe
    const int statsQ = (8 * 256) / 4;    // includes counters page
    const int zeroQ  = sbufQ + slotsQ + degQ + statsQ;
    const int zero_blocks = (zeroQ + 255) / 256;

    prep_kernel<<<640 + g16_blocks + zero_blocks, 256, 0, stream>>>(
        cw1, cw2, nmu_w, nlv_w, gmu_w, glv_w, whi, wlo,
        x, xbf, N * 16, g16_blocks,
        (float4*)sbuf, sbufQ, (float4*)slots, slotsQ,
        (float4*)deg, degQ, (float4*)stats, statsQ);

    hist_kernel<<<edge_blocks, 256, 0, stream>>>(dst, deg, E);
    alloc_kernel<<<scan_blocks, 256, 0, stream>>>(deg, rstart, cur, cnts, N);
    fill_kernel<<<edge_blocks, 256, 0, stream>>>(src, dst, cur, eidx, E);

    // layers: l0 xbf->rA, l1 rA->rB, l2 rB->rA (ping-pong); stats merged in-kernel
    const ushortT* lin[3]  = {xbf, rA, rB};
    ushortT*       lout[3] = {rA, rB, rA};
    for (int l = 0; l < 3; ++l) {
        const float* sprev  = (l == 0) ? nullptr : SB(l - 1);
        const float* g_prev = (l == 0) ? nullptr : bng + (size_t)(l - 1) * DIM;
        const float* b_prev = (l == 0) ? nullptr : bnb + (size_t)(l - 1) * DIM;
        layer_fused_kernel<<<layer_blocks, 256, 0, stream>>>(
            lin[l], rstart, deg, eidx,
            sprev, g_prev, b_prev,
            whi + (size_t)l * 16384, wlo + (size_t)l * 16384, cb1 + (size_t)l * DIM,
            whi + (size_t)(3 + l) * 16384, wlo + (size_t)(3 + l) * 16384, cb2 + (size_t)l * DIM,
            lout[l], SB(l), N, invN);
    }
    ushortT* rfin = rA;   // layer-2 output
    ushortT* hA   = rB;   // free after layer 2
    ushortT* hB   = xbf;  // free after layer 0

    // fused weigh+split+node-heads
    weigh_heads_kernel<<<heads_blocks, 256, 0, stream>>>(
        rfin, batch, SB(2), bng + 2 * DIM, bnb + 2 * DIM,
        sw_w, sw_b, slots,
        whi + (size_t)6 * 16384, wlo + (size_t)6 * 16384, nmu_b, hA, SB(3),
        whi + (size_t)7 * 16384, wlo + (size_t)7 * 16384, nlv_b, hB, SB(4),
        N, invN);

    // BN apply for both node heads; stripe merge in-kernel, grid-stride
    const int bn_nbh = 256;
    bn_dual_bf16_kernel<<<2 * bn_nbh, 256, 0, stream>>>(
        hA, out0, SB(3), hgam + 0 * DIM, hbet + 0 * DIM,
        hB, out1, SB(4), hgam + 1 * DIM, hbet + 1 * DIM, N, bn_nbh);

    // graph heads: both GEMMs + BN fused (last-block applies BN)
    const int gemm_blocks_G = (G + 63) / 64;
    gemm_graph_dual_bn_kernel<<<2 * gemm_blocks_G, 256, 0, stream>>>(
        slots,
        whi + (size_t)8 * 16384, wlo + (size_t)8 * 16384, gmu_b, out2, SS5,
        hgam + 2 * DIM, hbet + 2 * DIM, cnts + 1,
        whi + (size_t)9 * 16384, wlo + (size_t)9 * 16384, glv_b, out3, SS6,
        hgam + 3 * DIM, hbet + 3 * DIM, cnts + 2,
        G, gemm_blocks_G);
}

// Round 9
// 448.968 us; speedup vs baseline: 1.0285x; 1.0285x over previous
//
#include <hip/hip_runtime.h>
#include <hip/hip_bf16.h>

#define DIM 128
#define BN_EPS 1e-5f
#define NSTRIPE 32

typedef unsigned short ushortT;
typedef __attribute__((ext_vector_type(8))) short short8;
typedef __attribute__((ext_vector_type(4))) float floatx4;

__device__ __forceinline__ float bflo(unsigned u) { return __uint_as_float(u << 16); }
__device__ __forceinline__ float bfhi(unsigned u) { return __uint_as_float(u & 0xffff0000u); }
__device__ __forceinline__ float bf2f(ushortT h) { return __uint_as_float(((unsigned)h) << 16); }
__device__ __forceinline__ ushortT f2bf(float f) {
    unsigned x = __float_as_uint(f);
    unsigned r = (x + 0x7fff + ((x >> 16) & 1)) >> 16;
    return (ushortT)r;
}
__device__ __forceinline__ void decode8(const unsigned* ap, short8& hi, short8& lo) {
#pragma unroll
    for (int j = 0; j < 8; ++j) {
        hi[j] = (short)(ap[j] >> 16);
        lo[j] = (short)(ap[j] & 0xffffu);
    }
}
__device__ __forceinline__ void acc8(float* a, uint4 v) {
    a[0] += bflo(v.x); a[1] += bfhi(v.x);
    a[2] += bflo(v.y); a[3] += bfhi(v.y);
    a[4] += bflo(v.z); a[5] += bfhi(v.z);
    a[6] += bflo(v.w); a[7] += bfhi(v.w);
}

// ---------------- CSR build ----------------
__global__ __launch_bounds__(256) void hist_kernel(
    const int* __restrict__ dst, int* __restrict__ deg, int E)
{
    int e = blockIdx.x * 256 + threadIdx.x;
    if (e < E) atomicAdd(&deg[dst[e]], 1);
}

// ---- range alloc: block-local scan + 1 atomic per block (replaces scan1+scan2+scan3) ----
__global__ __launch_bounds__(256) void alloc_kernel(
    const int* __restrict__ deg, int* __restrict__ rstart,
    int* __restrict__ cur, int* __restrict__ total, int N)
{
    __shared__ int s[256];
    __shared__ int base;
    int t = threadIdx.x;
    int i = blockIdx.x * 256 + t;
    int v = (i < N) ? deg[i] : 0;
    s[t] = v;
    __syncthreads();
#pragma unroll
    for (int off = 1; off < 256; off <<= 1) {
        int u = (t >= off) ? s[t - off] : 0;
        __syncthreads();
        s[t] += u;
        __syncthreads();
    }
    if (t == 255) base = atomicAdd(total, s[255]);
    __syncthreads();
    if (i < N) {
        int pos = base + s[t] - v;
        rstart[i] = pos;
        cur[i] = pos;
    }
}

__global__ __launch_bounds__(256) void fill_kernel(
    const int* __restrict__ src, const int* __restrict__ dst,
    int* __restrict__ cur, int* __restrict__ eidx, int E)
{
    int e = blockIdx.x * 256 + threadIdx.x;
    if (e < E) {
        int pos = atomicAdd(&cur[dst[e]], 1);
        eidx[pos] = src[e];
    }
}

// ---- prep: weights->bf16 planes + x->bf16 + zero-fill ----
__global__ __launch_bounds__(256) void prep_kernel(
    const float* __restrict__ cw1, const float* __restrict__ cw2,
    const float* __restrict__ nmu, const float* __restrict__ nlv,
    const float* __restrict__ gmu, const float* __restrict__ glv,
    ushortT* __restrict__ whi, ushortT* __restrict__ wlo,
    const float* __restrict__ x, ushortT* __restrict__ xb, int n8, int cxBlocks,
    float4* __restrict__ zsbuf, int sbufQ,
    float4* __restrict__ zslots, int slotsQ,
    float4* __restrict__ zdeg, int degQ,
    float4* __restrict__ zstats, int statsQ)
{
    int b = blockIdx.x, t = threadIdx.x;
    if (b < 640) {
        int tid = b * 256 + t; // 10*16384
        int mat = tid >> 14;
        int i   = tid & 16383;
        int n = i >> 7, k = i & 127;
        const float* Wm = (mat < 3) ? cw1 + (size_t)mat * 16384
                        : (mat < 6) ? cw2 + (size_t)(mat - 3) * 16384
                        : (mat == 6) ? nmu : (mat == 7) ? nlv
                        : (mat == 8) ? gmu : glv;
        float w = Wm[k * DIM + n];
        ushortT h = f2bf(w);
        whi[(size_t)mat * 16384 + i] = h;
        wlo[(size_t)mat * 16384 + i] = f2bf(w - bf2f(h));
    } else if (b < 640 + cxBlocks) {
        int i = (b - 640) * 256 + t;
        if (i < n8) {
            const float4* xp = (const float4*)x;
            float4 a = xp[2 * i], bb = xp[2 * i + 1];
            uint4 o;
            o.x = (unsigned)f2bf(a.x) | ((unsigned)f2bf(a.y) << 16);
            o.y = (unsigned)f2bf(a.z) | ((unsigned)f2bf(a.w) << 16);
            o.z = (unsigned)f2bf(bb.x) | ((unsigned)f2bf(bb.y) << 16);
            o.w = (unsigned)f2bf(bb.z) | ((unsigned)f2bf(bb.w) << 16);
            ((uint4*)xb)[i] = o;
        }
    } else {
        int q = (b - 640 - cxBlocks) * 256 + t;
        float4 z = make_float4(0.f, 0.f, 0.f, 0.f);
        if (q < sbufQ) zsbuf[q] = z;
        else if ((q -= sbufQ) < slotsQ) zslots[q] = z;
        else if ((q -= slotsQ) < degQ) zdeg[q] = z;
        else if ((q -= degQ) < statsQ) zstats[q] = z;
    }
}

// ---- fused GIN layer (round-3 known-good gather; rstart/deg row ranges) ----
__global__ __launch_bounds__(256) void layer_fused_kernel(
    const ushortT* __restrict__ Xb, const int* __restrict__ rstart,
    const int* __restrict__ degp, const int* __restrict__ eidx,
    const float* __restrict__ sprev,
    const float* __restrict__ gamma, const float* __restrict__ beta,
    const ushortT* __restrict__ W1hi, const ushortT* __restrict__ W1lo,
    const float* __restrict__ b1,
    const ushortT* __restrict__ W2hi, const ushortT* __restrict__ W2lo,
    const float* __restrict__ b2,
    ushortT* __restrict__ rout, float* __restrict__ sdst,
    int M, float invM)
{
    __shared__ unsigned As[32][DIM + 4];
    __shared__ float ls[DIM], lsq[DIM];
    __shared__ float pstat[256];
    int t = threadIdx.x;
    int wave = t >> 6, lane = t & 63, quad = lane >> 4, l16 = lane & 15;
    int m0 = blockIdx.x * 32;

    if (sprev) {
        float s = 0.f;
#pragma unroll
        for (int i = 0; i < NSTRIPE; ++i) s += sprev[i * 256 + t];
        pstat[t] = s;
    }
    if (t < DIM) { ls[t] = 0.f; lsq[t] = 0.f; }
    __syncthreads();

    // ---- gather phase: 8 lanes per node, 16 cols each; edge loop unrolled x4 ----
    {
        int nloc = t >> 3;
        int c0   = (t & 7) * 16;
        int node = m0 + nloc;
        float acc[16];
#pragma unroll
        for (int j = 0; j < 16; ++j) acc[j] = 0.f;
        if (node < M) {
            int b = rstart[node];
            int dg = degp[node];
            int e = b + dg;
            const ushortT* xrow = Xb + (size_t)node * DIM + c0;
            acc8(&acc[0], *(const uint4*)(xrow));
            acc8(&acc[8], *(const uint4*)(xrow + 8));
            int i = b;
            for (; i + 4 <= e; i += 4) {
                int s0 = eidx[i], s1 = eidx[i + 1], s2 = eidx[i + 2], s3 = eidx[i + 3];
                const ushortT* p0 = Xb + (size_t)s0 * DIM + c0;
                const ushortT* p1 = Xb + (size_t)s1 * DIM + c0;
                const ushortT* p2 = Xb + (size_t)s2 * DIM + c0;
                const ushortT* p3 = Xb + (size_t)s3 * DIM + c0;
                uint4 v00 = *(const uint4*)(p0), v01 = *(const uint4*)(p0 + 8);
                uint4 v10 = *(const uint4*)(p1), v11 = *(const uint4*)(p1 + 8);
                uint4 v20 = *(const uint4*)(p2), v21 = *(const uint4*)(p2 + 8);
                uint4 v30 = *(const uint4*)(p3), v31 = *(const uint4*)(p3 + 8);
                acc8(&acc[0], v00); acc8(&acc[8], v01);
                acc8(&acc[0], v10); acc8(&acc[8], v11);
                acc8(&acc[0], v20); acc8(&acc[8], v21);
                acc8(&acc[0], v30); acc8(&acc[8], v31);
            }
            for (; i < e; ++i) {
                const ushortT* sp = Xb + (size_t)eidx[i] * DIM + c0;
                acc8(&acc[0], *(const uint4*)(sp));
                acc8(&acc[8], *(const uint4*)(sp + 8));
            }
            if (sprev) {
                float cnt = (float)(dg + 1);
#pragma unroll
                for (int jq = 0; jq < 4; ++jq) {
                    int c = c0 + jq * 4;
                    float4 sm = *(const float4*)&pstat[c];
                    float4 sq = *(const float4*)&pstat[128 + c];
                    float4 gm = *(const float4*)(gamma + c);
                    float4 bt = *(const float4*)(beta + c);
                    float m, sc;
                    m = sm.x * invM; sc = gm.x * rsqrtf(sq.x * invM - m * m + BN_EPS);
                    acc[jq * 4 + 0] = sc * acc[jq * 4 + 0] + cnt * (bt.x - sc * m);
                    m = sm.y * invM; sc = gm.y * rsqrtf(sq.y * invM - m * m + BN_EPS);
                    acc[jq * 4 + 1] = sc * acc[jq * 4 + 1] + cnt * (bt.y - sc * m);
                    m = sm.z * invM; sc = gm.z * rsqrtf(sq.z * invM - m * m + BN_EPS);
                    acc[jq * 4 + 2] = sc * acc[jq * 4 + 2] + cnt * (bt.z - sc * m);
                    m = sm.w * invM; sc = gm.w * rsqrtf(sq.w * invM - m * m + BN_EPS);
                    acc[jq * 4 + 3] = sc * acc[jq * 4 + 3] + cnt * (bt.w - sc * m);
                }
            }
        }
        unsigned pk[16];
#pragma unroll
        for (int j = 0; j < 16; ++j) {
            ushortT h = f2bf(acc[j]);
            ushortT l = f2bf(acc[j] - bf2f(h));
            pk[j] = ((unsigned)h << 16) | l;
        }
#pragma unroll
        for (int j4 = 0; j4 < 4; ++j4)
            *(uint4*)&As[nloc][c0 + j4 * 4] = *(uint4*)&pk[j4 * 4];
    }
    __syncthreads();

    int cbase = wave * 32;
    floatx4 acc[2][2];
#pragma unroll
    for (int mt = 0; mt < 2; ++mt)
#pragma unroll
        for (int nt = 0; nt < 2; ++nt)
            acc[mt][nt] = (floatx4){0.f, 0.f, 0.f, 0.f};

    // ---- GEMM1 ----
#pragma unroll
    for (int ks = 0; ks < 4; ++ks) {
        int k0 = ks * 32 + quad * 8;
        short8 bhi[2], blo[2];
#pragma unroll
        for (int nt = 0; nt < 2; ++nt) {
            const size_t woff = (size_t)(cbase + nt * 16 + l16) * DIM + k0;
            bhi[nt] = *(const short8*)(W1hi + woff);
            blo[nt] = *(const short8*)(W1lo + woff);
        }
#pragma unroll
        for (int mt = 0; mt < 2; ++mt) {
            int lr = mt * 16 + l16;
            unsigned ap[8];
            *(uint4*)&ap[0] = *(const uint4*)&As[lr][k0];
            *(uint4*)&ap[4] = *(const uint4*)&As[lr][k0 + 4];
            short8 ahi, alo;
            decode8(ap, ahi, alo);
#pragma unroll
            for (int nt = 0; nt < 2; ++nt) {
                acc[mt][nt] = __builtin_amdgcn_mfma_f32_16x16x32_bf16(ahi, bhi[nt], acc[mt][nt], 0, 0, 0);
                acc[mt][nt] = __builtin_amdgcn_mfma_f32_16x16x32_bf16(alo, bhi[nt], acc[mt][nt], 0, 0, 0);
                acc[mt][nt] = __builtin_amdgcn_mfma_f32_16x16x32_bf16(ahi, blo[nt], acc[mt][nt], 0, 0, 0);
            }
        }
    }
    __syncthreads();

    // epilogue 1 -> LDS
#pragma unroll
    for (int nt = 0; nt < 2; ++nt) {
        int col = cbase + nt * 16 + l16;
        float bcol = b1[col];
#pragma unroll
        for (int mt = 0; mt < 2; ++mt)
#pragma unroll
            for (int r = 0; r < 4; ++r) {
                int lr = mt * 16 + quad * 4 + r;
                float v = fmaxf(acc[mt][nt][r] + bcol, 0.f);
                ushortT hv = f2bf(v);
                ushortT lv = f2bf(v - bf2f(hv));
                As[lr][col] = ((unsigned)hv << 16) | lv;
            }
    }
    __syncthreads();

    // ---- GEMM2 ----
#pragma unroll
    for (int mt = 0; mt < 2; ++mt)
#pragma unroll
        for (int nt = 0; nt < 2; ++nt)
            acc[mt][nt] = (floatx4){0.f, 0.f, 0.f, 0.f};

#pragma unroll
    for (int ks = 0; ks < 4; ++ks) {
        int k0 = ks * 32 + quad * 8;
        short8 bhi[2], blo[2];
#pragma unroll
        for (int nt = 0; nt < 2; ++nt) {
            const size_t woff = (size_t)(cbase + nt * 16 + l16) * DIM + k0;
            bhi[nt] = *(const short8*)(W2hi + woff);
            blo[nt] = *(const short8*)(W2lo + woff);
        }
#pragma unroll
        for (int mt = 0; mt < 2; ++mt) {
            int lr = mt * 16 + l16;
            unsigned ap[8];
            *(uint4*)&ap[0] = *(const uint4*)&As[lr][k0];
            *(uint4*)&ap[4] = *(const uint4*)&As[lr][k0 + 4];
            short8 ahi, alo;
            decode8(ap, ahi, alo);
#pragma unroll
            for (int nt = 0; nt < 2; ++nt) {
                acc[mt][nt] = __builtin_amdgcn_mfma_f32_16x16x32_bf16(ahi, bhi[nt], acc[mt][nt], 0, 0, 0);
                acc[mt][nt] = __builtin_amdgcn_mfma_f32_16x16x32_bf16(alo, bhi[nt], acc[mt][nt], 0, 0, 0);
                acc[mt][nt] = __builtin_amdgcn_mfma_f32_16x16x32_bf16(ahi, blo[nt], acc[mt][nt], 0, 0, 0);
            }
        }
    }
    // epilogue 2
#pragma unroll
    for (int nt = 0; nt < 2; ++nt) {
        int col = cbase + nt * 16 + l16;
        float bcol = b2[col];
        float s = 0.f, sq = 0.f;
#pragma unroll
        for (int mt = 0; mt < 2; ++mt)
#pragma unroll
            for (int r = 0; r < 4; ++r) {
                int gr = m0 + mt * 16 + quad * 4 + r;
                if (gr < M) {
                    float v = fmaxf(acc[mt][nt][r] + bcol, 0.f);
                    rout[(size_t)gr * DIM + col] = f2bf(v);
                    s += v;
                    sq += v * v;
                }
            }
        s  += __shfl_xor(s, 16);  s  += __shfl_xor(s, 32);
        sq += __shfl_xor(sq, 16); sq += __shfl_xor(sq, 32);
        if (quad == 0) {
            atomicAdd(&ls[col], s);
            atomicAdd(&lsq[col], sq);
        }
    }
    __syncthreads();
    float* dstp = sdst + (size_t)(blockIdx.x & (NSTRIPE - 1)) * 256;
    if (t < 128) atomicAdd(&dstp[t], ls[t]);
    else         atomicAdd(&dstp[t], lsq[t - 128]);
}

// ---- fused weigh+split+node-heads (round-7, verified) ----
__global__ __launch_bounds__(256) void weigh_heads_kernel(
    const ushortT* __restrict__ R, const int* __restrict__ batch,
    const float* __restrict__ sprev,
    const float* __restrict__ gamma, const float* __restrict__ beta,
    const float* __restrict__ sw_w, const float* __restrict__ sw_b,
    float* __restrict__ slots,
    const ushortT* __restrict__ WAhi, const ushortT* __restrict__ WAlo,
    const float* __restrict__ bA, ushortT* __restrict__ hA, float* __restrict__ sdstA,
    const ushortT* __restrict__ WBhi, const ushortT* __restrict__ WBlo,
    const float* __restrict__ bB, ushortT* __restrict__ hB, float* __restrict__ sdstB,
    int N, float invM)
{
    __shared__ unsigned As[64][DIM + 4];
    __shared__ float pstat[256];
    __shared__ float part[256];
    __shared__ float wsh[64];
    __shared__ float lsA[DIM], lsqA[DIM], lsB[DIM], lsqB[DIM];
    int t = threadIdx.x;
    int wave = t >> 6, lane = t & 63, quad = lane >> 4, l16 = lane & 15;
    int m0 = blockIdx.x * 64;

    {
        float s = 0.f;
#pragma unroll
        for (int i = 0; i < NSTRIPE; ++i) s += sprev[i * 256 + t];
        pstat[t] = s;
    }
    if (t < DIM) { lsA[t] = 0.f; lsqA[t] = 0.f; lsB[t] = 0.f; lsqB[t] = 0.f; }
    __syncthreads();

    // phase A: per-row dot for w
    {
        int row = m0 + (t >> 2);
        int cs  = (t & 3) * 32;
        float d = 0.f;
        if (row < N) {
            for (int c = cs; c < cs + 32; c += 4) {
                uint2 u = *(const uint2*)(R + (size_t)row * DIM + c);
                float rv[4] = {bflo(u.x), bfhi(u.x), bflo(u.y), bfhi(u.y)};
                float4 sm = *(const float4*)&pstat[c];
                float4 sq = *(const float4*)&pstat[128 + c];
                float4 gm = *(const float4*)(gamma + c);
                float4 bt = *(const float4*)(beta + c);
                float4 sw = *(const float4*)(sw_w + c);
                float m, sc;
                m = sm.x * invM; sc = gm.x * rsqrtf(sq.x * invM - m * m + BN_EPS);
                d += (sc * (rv[0] - m) + bt.x) * sw.x;
                m = sm.y * invM; sc = gm.y * rsqrtf(sq.y * invM - m * m + BN_EPS);
                d += (sc * (rv[1] - m) + bt.y) * sw.y;
                m = sm.z * invM; sc = gm.z * rsqrtf(sq.z * invM - m * m + BN_EPS);
                d += (sc * (rv[2] - m) + bt.z) * sw.z;
                m = sm.w * invM; sc = gm.w * rsqrtf(sq.w * invM - m * m + BN_EPS);
                d += (sc * (rv[3] - m) + bt.w) * sw.w;
            }
        }
        part[t] = d;
    }
    __syncthreads();
    if (t < 64) {
        float dd = part[4 * t] + part[4 * t + 1] + part[4 * t + 2] + part[4 * t + 3];
        wsh[t] = 1.0f / (1.0f + expf(-(dd + sw_b[0])));
    }
    __syncthreads();

    // phase B: noisy -> LDS, slots += w*bn(r)
    {
        int c    = t & 127;
        int half = t >> 7;
        float m   = pstat[c] * invM;
        float var = pstat[128 + c] * invM - m * m;
        float sc  = gamma[c] * rsqrtf(var + BN_EPS);
        float sh  = beta[c] - sc * m;
        int curg = -1;
        float acc = 0.f;
        for (int r = half; r < 64; r += 2) {
            int row = m0 + r;
            if (row < N) {
                float xv = sc * bf2f(R[(size_t)row * DIM + c]) + sh;
                float w  = wsh[r];
                float nv = (1.f - w) * xv;
                ushortT hv = f2bf(nv);
                ushortT lv = f2bf(nv - bf2f(hv));
                As[r][c] = ((unsigned)hv << 16) | lv;
                int g = batch[row];
                if (g != curg) {
                    if (curg >= 0) atomicAdd(&slots[(size_t)curg * DIM + c], acc);
                    curg = g;
                    acc = 0.f;
                }
                acc += w * xv;
            } else {
                As[r][c] = 0;
            }
        }
        if (curg >= 0) atomicAdd(&slots[(size_t)curg * DIM + c], acc);
    }
    __syncthreads();

    // phase C: dual-head GEMM from LDS
    int cbase = wave * 32;
    floatx4 accA[4][2], accB[4][2];
#pragma unroll
    for (int mt = 0; mt < 4; ++mt)
#pragma unroll
        for (int nt = 0; nt < 2; ++nt) {
            accA[mt][nt] = (floatx4){0.f, 0.f, 0.f, 0.f};
            accB[mt][nt] = (floatx4){0.f, 0.f, 0.f, 0.f};
        }

    for (int ks = 0; ks < 4; ++ks) {
        int k0 = ks * 32 + quad * 8;
        short8 bAhi[2], bAlo[2], bBhi[2], bBlo[2];
#pragma unroll
        for (int nt = 0; nt < 2; ++nt) {
            const size_t woff = (size_t)(cbase + nt * 16 + l16) * DIM + k0;
            bAhi[nt] = *(const short8*)(WAhi + woff);
            bAlo[nt] = *(const short8*)(WAlo + woff);
            bBhi[nt] = *(const short8*)(WBhi + woff);
            bBlo[nt] = *(const short8*)(WBlo + woff);
        }
#pragma unroll
        for (int mt = 0; mt < 4; ++mt) {
            int lr = mt * 16 + l16;
            unsigned ap[8];
            *(uint4*)&ap[0] = *(const uint4*)&As[lr][k0];
            *(uint4*)&ap[4] = *(const uint4*)&As[lr][k0 + 4];
            short8 ahi, alo;
            decode8(ap, ahi, alo);
#pragma unroll
            for (int nt = 0; nt < 2; ++nt) {
                accA[mt][nt] = __builtin_amdgcn_mfma_f32_16x16x32_bf16(ahi, bAhi[nt], accA[mt][nt], 0, 0, 0);
                accA[mt][nt] = __builtin_amdgcn_mfma_f32_16x16x32_bf16(alo, bAhi[nt], accA[mt][nt], 0, 0, 0);
                accA[mt][nt] = __builtin_amdgcn_mfma_f32_16x16x32_bf16(ahi, bAlo[nt], accA[mt][nt], 0, 0, 0);
                accB[mt][nt] = __builtin_amdgcn_mfma_f32_16x16x32_bf16(ahi, bBhi[nt], accB[mt][nt], 0, 0, 0);
                accB[mt][nt] = __builtin_amdgcn_mfma_f32_16x16x32_bf16(alo, bBhi[nt], accB[mt][nt], 0, 0, 0);
                accB[mt][nt] = __builtin_amdgcn_mfma_f32_16x16x32_bf16(ahi, bBlo[nt], accB[mt][nt], 0, 0, 0);
            }
        }
    }

#pragma unroll
    for (int nt = 0; nt < 2; ++nt) {
        int col = cbase + nt * 16 + l16;
        float bcA = bA[col], bcB = bB[col];
        float sA = 0.f, sqA = 0.f, sB = 0.f, sqB = 0.f;
#pragma unroll
        for (int mt = 0; mt < 4; ++mt)
#pragma unroll
            for (int r = 0; r < 4; ++r) {
                int gr = m0 + mt * 16 + quad * 4 + r;
                if (gr < N) {
                    size_t off = (size_t)gr * DIM + col;
                    float vA = fmaxf(accA[mt][nt][r] + bcA, 0.f);
                    float vB = fmaxf(accB[mt][nt][r] + bcB, 0.f);
                    hA[off] = f2bf(vA);
                    hB[off] = f2bf(vB);
                    sA += vA; sqA += vA * vA;
                    sB += vB; sqB += vB * vB;
                }
            }
        sA += __shfl_xor(sA, 16);  sA += __shfl_xor(sA, 32);
        sqA += __shfl_xor(sqA, 16); sqA += __shfl_xor(sqA, 32);
        sB += __shfl_xor(sB, 16);  sB += __shfl_xor(sB, 32);
        sqB += __shfl_xor(sqB, 16); sqB += __shfl_xor(sqB, 32);
        if (quad == 0) {
            atomicAdd(&lsA[col], sA);
            atomicAdd(&lsqA[col], sqA);
            atomicAdd(&lsB[col], sB);
            atomicAdd(&lsqB[col], sqB);
        }
    }
    __syncthreads();
    int stripe = blockIdx.x & (NSTRIPE - 1);
    float* dA = sdstA + (size_t)stripe * 256;
    float* dB = sdstB + (size_t)stripe * 256;
    if (t < 128) { atomicAdd(&dA[t], lsA[t]); atomicAdd(&dB[t], lsB[t]); }
    else         { atomicAdd(&dA[t], lsqA[t - 128]); atomicAdd(&dB[t], lsqB[t - 128]); }
}

// ---- merge 32 stat stripes for two buffers, grid=2 ----
__global__ __launch_bounds__(256) void merge_stats2_kernel(
    const float* __restrict__ sA, float* __restrict__ oA,
    const float* __restrict__ sB, float* __restrict__ oB)
{
    const float* s = blockIdx.x ? sB : sA;
    float* o = blockIdx.x ? oB : oA;
    int t = threadIdx.x;
    float v = 0.f;
#pragma unroll
    for (int i = 0; i < NSTRIPE; ++i) v += s[i * 256 + t];
    o[t] = v;
}

// ---- both graph-head GEMMs in one launch (fp32 A, in-kernel decompose, direct stats) ----
__global__ __launch_bounds__(256) void gemm_graph_dual_kernel(
    const float* __restrict__ A32,
    const ushortT* __restrict__ W8hi, const ushortT* __restrict__ W8lo,
    const float* __restrict__ b8, float* __restrict__ C8, float* __restrict__ st8,
    const ushortT* __restrict__ W9hi, const ushortT* __restrict__ W9lo,
    const float* __restrict__ b9, float* __restrict__ C9, float* __restrict__ st9,
    int M, int nb)
{
    __shared__ float ls[DIM], lsq[DIM];
    int bb = blockIdx.x;
    const ushortT* Whi; const ushortT* Wlo; const float* bias; float* C; float* st;
    if (bb < nb) { Whi = W8hi; Wlo = W8lo; bias = b8; C = C8; st = st8; }
    else { bb -= nb; Whi = W9hi; Wlo = W9lo; bias = b9; C = C9; st = st9; }

    int t     = threadIdx.x;
    int wave  = t >> 6;
    int lane  = t & 63;
    int quad  = lane >> 4;
    int l16   = lane & 15;
    int m0    = bb * 64;
    int cbase = wave * 32;

    if (t < DIM) { ls[t] = 0.f; lsq[t] = 0.f; }
    __syncthreads();

    floatx4 acc[4][2];
#pragma unroll
    for (int mt = 0; mt < 4; ++mt)
#pragma unroll
        for (int nt = 0; nt < 2; ++nt)
            acc[mt][nt] = (floatx4){0.f, 0.f, 0.f, 0.f};

    for (int ks = 0; ks < 4; ++ks) {
        int k0 = ks * 32 + quad * 8;
        short8 bhi[2], blo[2];
#pragma unroll
        for (int nt = 0; nt < 2; ++nt) {
            const size_t woff = (size_t)(cbase + nt * 16 + l16) * DIM + k0;
            bhi[nt] = *(const short8*)(Whi + woff);
            blo[nt] = *(const short8*)(Wlo + woff);
        }
#pragma unroll
        for (int mt = 0; mt < 4; ++mt) {
            int row = m0 + mt * 16 + l16;
            short8 ahi = {0,0,0,0,0,0,0,0};
            short8 alo = {0,0,0,0,0,0,0,0};
            if (row < M) {
                float av[8];
                *(float4*)&av[0] = *(const float4*)(A32 + (size_t)row * DIM + k0);
                *(float4*)&av[4] = *(const float4*)(A32 + (size_t)row * DIM + k0 + 4);
#pragma unroll
                for (int j = 0; j < 8; ++j) {
                    ushortT hv = f2bf(av[j]);
                    ahi[j] = (short)hv;
                    alo[j] = (short)f2bf(av[j] - bf2f(hv));
                }
            }
#pragma unroll
            for (int nt = 0; nt < 2; ++nt) {
                acc[mt][nt] = __builtin_amdgcn_mfma_f32_16x16x32_bf16(ahi, bhi[nt], acc[mt][nt], 0, 0, 0);
                acc[mt][nt] = __builtin_amdgcn_mfma_f32_16x16x32_bf16(alo, bhi[nt], acc[mt][nt], 0, 0, 0);
                acc[mt][nt] = __builtin_amdgcn_mfma_f32_16x16x32_bf16(ahi, blo[nt], acc[mt][nt], 0, 0, 0);
            }
        }
    }

#pragma unroll
    for (int nt = 0; nt < 2; ++nt) {
        int col = cbase + nt * 16 + l16;
        float bcol = bias[col];
        float s = 0.f, sq = 0.f;
#pragma unroll
        for (int mt = 0; mt < 4; ++mt)
#pragma unroll
            for (int r = 0; r < 4; ++r) {
                int gr = m0 + mt * 16 + quad * 4 + r;
                if (gr < M) {
                    float v = fmaxf(acc[mt][nt][r] + bcol, 0.f);
                    C[(size_t)gr * DIM + col] = v;
                    s += v;
                    sq += v * v;
                }
            }
        s  += __shfl_xor(s, 16);  s  += __shfl_xor(s, 32);
        sq += __shfl_xor(sq, 16); sq += __shfl_xor(sq, 32);
        if (quad == 0) {
            atomicAdd(&ls[col], s);
            atomicAdd(&lsq[col], sq);
        }
    }
    __syncthreads();
    if (t < DIM) {
        atomicAdd(&st[t], ls[t]);
        atomicAdd(&st[DIM + t], lsq[t]);
    }
}

// ---- BN apply, two bf16 planes -> two fp32 outs, one launch ----
__global__ __launch_bounds__(256) void bn_dual_bf16_kernel(
    const ushortT* __restrict__ RA, float* __restrict__ OA, const float* __restrict__ stA,
    const float* __restrict__ gA, const float* __restrict__ bA,
    const ushortT* __restrict__ RB, float* __restrict__ OB, const float* __restrict__ stB,
    const float* __restrict__ gB, const float* __restrict__ bB,
    int M, int nb)
{
    int bb = blockIdx.x;
    const ushortT* R; float* O; const float* st; const float* gamma; const float* beta;
    if (bb < nb) { R = RA; O = OA; st = stA; gamma = gA; beta = bA; }
    else { bb -= nb; R = RB; O = OB; st = stB; gamma = gB; beta = bB; }
    int idx = bb * 256 + threadIdx.x; // over M*32 col-quads
    if (idx >= M * 32) return;
    int c4 = idx & 31;
    float invM = 1.0f / (float)M;
    uint2 u = ((const uint2*)R)[idx];
    float o[4] = {bflo(u.x), bfhi(u.x), bflo(u.y), bfhi(u.y)};
#pragma unroll
    for (int j = 0; j < 4; ++j) {
        int c = c4 * 4 + j;
        float m   = st[c] * invM;
        float var = st[DIM + c] * invM - m * m;
        float sc  = gamma[c] * rsqrtf(var + BN_EPS);
        o[j] = sc * (o[j] - m) + beta[c];
    }
    ((float4*)O)[idx] = make_float4(o[0], o[1], o[2], o[3]);
}

// ---- BN apply, two fp32 planes in-place, one launch (graph heads) ----
__global__ __launch_bounds__(256) void bn_dual_f32_kernel(
    float* __restrict__ CA, const float* __restrict__ stA,
    const float* __restrict__ gA, const float* __restrict__ bA,
    float* __restrict__ CB, const float* __restrict__ stB,
    const float* __restrict__ gB, const float* __restrict__ bB,
    int M, int nb)
{
    int bb = blockIdx.x;
    float* C; const float* st; const float* gamma; const float* beta;
    if (bb < nb) { C = CA; st = stA; gamma = gA; beta = bA; }
    else { bb -= nb; C = CB; st = stB; gamma = gB; beta = bB; }
    int idx = bb * 256 + threadIdx.x;
    if (idx >= M * 32) return;
    int c4 = idx & 31;
    float invM = 1.0f / (float)M;
    float4 v = ((const float4*)C)[idx];
    float o[4] = {v.x, v.y, v.z, v.w};
#pragma unroll
    for (int j = 0; j < 4; ++j) {
        int c = c4 * 4 + j;
        float m   = st[c] * invM;
        float var = st[DIM + c] * invM - m * m;
        float sc  = gamma[c] * rsqrtf(var + BN_EPS);
        o[j] = sc * (o[j] - m) + beta[c];
    }
    ((float4*)C)[idx] = make_float4(o[0], o[1], o[2], o[3]);
}

extern "C" void kernel_launch(void* const* d_in, const int* in_sizes, int n_in,
                              void* d_out, int out_size, void* d_ws, size_t ws_size,
                              hipStream_t stream)
{
    const float* x      = (const float*)d_in[0];
    const int*   src    = (const int*)d_in[1];
    const int*   dst    = (const int*)d_in[2];
    const int*   batch  = (const int*)d_in[3];
    const float* cw1    = (const float*)d_in[5];
    const float* cb1    = (const float*)d_in[6];
    const float* cw2    = (const float*)d_in[7];
    const float* cb2    = (const float*)d_in[8];
    const float* bng    = (const float*)d_in[9];
    const float* bnb    = (const float*)d_in[10];
    const float* sw_w   = (const float*)d_in[11];
    const float* sw_b   = (const float*)d_in[12];
    const float* nmu_b  = (const float*)d_in[14];
    const float* nlv_b  = (const float*)d_in[16];
    const float* gmu_b  = (const float*)d_in[18];
    const float* glv_b  = (const float*)d_in[20];
    const float* hgam   = (const float*)d_in[21];
    const float* hbet   = (const float*)d_in[22];
    const float* nmu_w  = (const float*)d_in[13];
    const float* nlv_w  = (const float*)d_in[15];
    const float* gmu_w  = (const float*)d_in[17];
    const float* glv_w  = (const float*)d_in[19];

    const int N = in_sizes[0] / DIM;
    const int E = in_sizes[1];
    const int G = (out_size / DIM - 2 * N) / 2;

    float* out0 = (float*)d_out;
    float* out1 = out0 + (size_t)N * DIM;
    float* out2 = out1 + (size_t)N * DIM;
    float* out3 = out2 + (size_t)G * DIM;

    // ---- workspace layout ----
    char* wp = (char*)d_ws;
    auto alloc = [&](size_t bytes) {
        char* p = wp;
        wp += (bytes + 255) & ~(size_t)255;
        return p;
    };
    ushortT*  xbf   = (ushortT*)alloc((size_t)N * DIM * 2);  // layer-0 input; later hB
    ushortT*  rA    = (ushortT*)alloc((size_t)N * DIM * 2);  // layer ping; final r
    ushortT*  rB    = (ushortT*)alloc((size_t)N * DIM * 2);  // layer pong; later hA
    unsigned* noisyP= (unsigned*)alloc((size_t)N * DIM * 4); // CSR temps overlay (deg live through layers)
    ushortT*  whi   = (ushortT*)alloc((size_t)10 * 16384 * 2);
    ushortT*  wlo   = (ushortT*)alloc((size_t)10 * 16384 * 2);
    float* slots    = (float*)alloc((size_t)G * DIM * 4);
    float* stats    = (float*)alloc((size_t)8 * 256 * 4);          // [sum|sq] x7 + counters page
    float* sbuf     = (float*)alloc((size_t)5 * NSTRIPE * 256 * 4);// stripe bufs x5
    int* rstart     = (int*)alloc((size_t)(N + 2) * 4);
    int* eidx       = (int*)alloc((size_t)E * 4);
    // CSR temps overlay in noisyP (deg/cur read through layers; nothing writes noisyP after fill)
    int* deg   = (int*)noisyP;
    int* cur   = deg + N;

    auto SS = [&](int i) { return stats + (size_t)i * 256; };
    auto SB = [&](int i) { return sbuf + (size_t)i * NSTRIPE * 256; };
    int* cnts = (int*)(stats + (size_t)7 * 256); // [0] = alloc total

    const int edge_blocks  = (E + 255) / 256;
    const int scan_blocks  = (N + 255) / 256;
    const int layer_blocks = (N + 31) / 32;
    const int heads_blocks = (N + 63) / 64;
    const int g16_blocks   = (N * 16 + 255) / 256;
    const int g32_blocks   = (N * 32 + 255) / 256;
    const float invN = 1.0f / (float)N;

    // zero-region geometry (float4 quads)
    const int sbufQ  = (5 * NSTRIPE * 256) / 4;
    const int slotsQ = (G * DIM) / 4;
    const int degQ   = (N + 3) / 4;      // may spill a few ints into noisyP body: safe
    const int statsQ = (8 * 256) / 4;    // includes counters page
    const int zeroQ  = sbufQ + slotsQ + degQ + statsQ;
    const int zero_blocks = (zeroQ + 255) / 256;

    prep_kernel<<<640 + g16_blocks + zero_blocks, 256, 0, stream>>>(
        cw1, cw2, nmu_w, nlv_w, gmu_w, glv_w, whi, wlo,
        x, xbf, N * 16, g16_blocks,
        (float4*)sbuf, sbufQ, (float4*)slots, slotsQ,
        (float4*)deg, degQ, (float4*)stats, statsQ);

    hist_kernel<<<edge_blocks, 256, 0, stream>>>(dst, deg, E);
    alloc_kernel<<<scan_blocks, 256, 0, stream>>>(deg, rstart, cur, cnts, N);
    fill_kernel<<<edge_blocks, 256, 0, stream>>>(src, dst, cur, eidx, E);

    // layers: l0 xbf->rA, l1 rA->rB, l2 rB->rA (ping-pong); stats merged in-kernel
    const ushortT* lin[3]  = {xbf, rA, rB};
    ushortT*       lout[3] = {rA, rB, rA};
    for (int l = 0; l < 3; ++l) {
        const float* sprev  = (l == 0) ? nullptr : SB(l - 1);
        const float* g_prev = (l == 0) ? nullptr : bng + (size_t)(l - 1) * DIM;
        const float* b_prev = (l == 0) ? nullptr : bnb + (size_t)(l - 1) * DIM;
        layer_fused_kernel<<<layer_blocks, 256, 0, stream>>>(
            lin[l], rstart, deg, eidx,
            sprev, g_prev, b_prev,
            whi + (size_t)l * 16384, wlo + (size_t)l * 16384, cb1 + (size_t)l * DIM,
            whi + (size_t)(3 + l) * 16384, wlo + (size_t)(3 + l) * 16384, cb2 + (size_t)l * DIM,
            lout[l], SB(l), N, invN);
    }
    ushortT* rfin = rA;   // layer-2 output
    ushortT* hA   = rB;   // free after layer 2
    ushortT* hB   = xbf;  // free after layer 0

    // fused weigh+split+node-heads
    weigh_heads_kernel<<<heads_blocks, 256, 0, stream>>>(
        rfin, batch, SB(2), bng + 2 * DIM, bnb + 2 * DIM,
        sw_w, sw_b, slots,
        whi + (size_t)6 * 16384, wlo + (size_t)6 * 16384, nmu_b, hA, SB(3),
        whi + (size_t)7 * 16384, wlo + (size_t)7 * 16384, nlv_b, hB, SB(4),
        N, invN);
    merge_stats2_kernel<<<2, 256, 0, stream>>>(SB(3), SS(3), SB(4), SS(4));
    bn_dual_bf16_kernel<<<2 * g32_blocks, 256, 0, stream>>>(
        hA, out0, SS(3), hgam + 0 * DIM, hbet + 0 * DIM,
        hB, out1, SS(4), hgam + 1 * DIM, hbet + 1 * DIM, N, g32_blocks);

    // graph heads (tiny): both GEMMs in one launch, both BNs in one launch
    const int gemm_blocks_G = (G + 63) / 64;
    const int gbn_blocks    = (G * 32 + 255) / 256;
    gemm_graph_dual_kernel<<<2 * gemm_blocks_G, 256, 0, stream>>>(
        slots,
        whi + (size_t)8 * 16384, wlo + (size_t)8 * 16384, gmu_b, out2, SS(5),
        whi + (size_t)9 * 16384, wlo + (size_t)9 * 16384, glv_b, out3, SS(6),
        G, gemm_blocks_G);
    bn_dual_f32_kernel<<<2 * gbn_blocks, 256, 0, stream>>>(
        out2, SS(5), hgam + 2 * DIM, hbet + 2 * DIM,
        out3, SS(6), hgam + 3 * DIM, hbet + 3 * DIM, G, gbn_blocks);
}